// Round 4
// baseline (1560.297 us; speedup 1.0000x reference)
//
#include <hip/hip_runtime.h>
#include <stdint.h>

#define N_TOK   65536
#define MDIM    2048
#define FDIM    512
#define SCALE_F 10.0f
#define TAU_F   2e-5f
#define QCAP    16384

typedef __attribute__((ext_vector_type(8))) unsigned short u16x8;
typedef __attribute__((ext_vector_type(8))) __bf16 bf16x8;
typedef __attribute__((ext_vector_type(4))) float f32x4;

__device__ __forceinline__ unsigned short f2bf(float f) {
  unsigned int u = __builtin_bit_cast(unsigned int, f);
  u += 0x7fffu + ((u >> 16) & 1u);   // round-to-nearest-even
  return (unsigned short)(u >> 16);
}
__device__ __forceinline__ float bf2f(unsigned short b) {
  return __builtin_bit_cast(float, (unsigned int)b << 16);
}
__device__ __forceinline__ f32x4 mfma16(u16x8 a, u16x8 b, f32x4 c) {
  return __builtin_amdgcn_mfma_f32_16x16x32_bf16(
      __builtin_bit_cast(bf16x8, a), __builtin_bit_cast(bf16x8, b), c, 0, 0, 0);
}

// ---------------- zero updates + queue counter ----------------
__global__ __launch_bounds__(256) void zero_k(float* __restrict__ updates,
                                              int* __restrict__ qcount) {
  const size_t i = ((size_t)blockIdx.x * 256 + threadIdx.x) * 4;
  *(float4*)(updates + i) = make_float4(0.f, 0.f, 0.f, 0.f);
  if (blockIdx.x == 0 && threadIdx.x == 0) *qcount = 0;
}

// ---------------- memory_norm -> bf16 hi/lo ----------------
__global__ __launch_bounds__(64) void prep_memory_k(
    const float* __restrict__ mem, unsigned short* __restrict__ Bh,
    unsigned short* __restrict__ Bl) {
  const int m = blockIdx.x;
  const int lane = threadIdx.x;
  const float* row = mem + (size_t)m * FDIM;
  float4 a = *(const float4*)(row + lane * 4);
  float4 b = *(const float4*)(row + 256 + lane * 4);
  float s = a.x * a.x + a.y * a.y + a.z * a.z + a.w * a.w +
            b.x * b.x + b.y * b.y + b.z * b.z + b.w * b.w;
  #pragma unroll
  for (int off = 1; off < 64; off <<= 1) s += __shfl_xor(s, off);
  const float rn = 1.0f / sqrtf(fmaxf(s, 1e-12f));
  float v[8] = {a.x, a.y, a.z, a.w, b.x, b.y, b.z, b.w};
  #pragma unroll
  for (int h = 0; h < 2; ++h) {
    ushort4 hs, lo;
    #pragma unroll
    for (int q = 0; q < 4; ++q) {
      float x = v[h * 4 + q] * rn;
      unsigned short hb = f2bf(x);
      ((unsigned short*)&hs)[q] = hb;
      ((unsigned short*)&lo)[q] = f2bf(x - bf2f(hb));
    }
    const size_t e = (size_t)m * FDIM + h * 256 + lane * 4;
    *(ushort4*)(Bh + e) = hs;
    *(ushort4*)(Bl + e) = lo;
  }
}

// ---------------- fp64 memory row inv-norms ----------------
__global__ __launch_bounds__(256) void mem_norms64_k(
    const float* __restrict__ mem, double* __restrict__ dmninv) {
  const int m = blockIdx.x * 4 + (threadIdx.x >> 6);
  const int lane = threadIdx.x & 63;
  const float* row = mem + (size_t)m * FDIM;
  double s = 0.0;
  #pragma unroll
  for (int j = 0; j < 8; ++j) {
    const double v = row[lane * 8 + j];
    s += v * v;
  }
  #pragma unroll
  for (int off = 1; off < 64; off <<= 1) s += __shfl_xor(s, off);
  if (lane == 0) dmninv[m] = 1.0 / sqrt(fmax(s, 1e-12));
}

// ---------------- transpose Bh [M][F] -> Bt [F][M] ----------------
__global__ __launch_bounds__(256) void transpose_k(
    const unsigned short* __restrict__ Bh, unsigned short* __restrict__ Bt) {
  __shared__ unsigned short t[32][33];
  const int m0 = blockIdx.x * 32, f0 = blockIdx.y * 32;
  const int tx = threadIdx.x & 31, ty = threadIdx.x >> 5;
  #pragma unroll
  for (int r = ty; r < 32; r += 8)
    t[r][tx] = Bh[(size_t)(m0 + r) * FDIM + f0 + tx];
  __syncthreads();
  #pragma unroll
  for (int r = ty; r < 32; r += 8)
    Bt[(size_t)(f0 + r) * MDIM + m0 + tx] = t[tx][r];
}

// ---------------- input row inv-norms (f32) ----------------
__global__ __launch_bounds__(256) void input_norms_k(
    const float* __restrict__ inp, float* __restrict__ inv_n) {
  const int row = blockIdx.x * 4 + (threadIdx.x >> 6);
  const int lane = threadIdx.x & 63;
  const float* x = inp + (size_t)row * FDIM;
  float4 a = *(const float4*)(x + lane * 4);
  float4 b = *(const float4*)(x + 256 + lane * 4);
  float s = a.x * a.x + a.y * a.y + a.z * a.z + a.w * a.w +
            b.x * b.x + b.y * b.y + b.z * b.z + b.w * b.w;
  #pragma unroll
  for (int off = 1; off < 64; off <<= 1) s += __shfl_xor(s, off);
  if (lane == 0) inv_n[row] = 1.0f / sqrtf(fmaxf(s, 1e-12f));
}

// ---------------- inputs_norm chunk -> bf16 hi/lo ----------------
__global__ __launch_bounds__(256) void prep_a_k(
    const float* __restrict__ inp, const float* __restrict__ inv_n,
    unsigned short* __restrict__ Ah, unsigned short* __restrict__ Al,
    int baseRow) {
  const size_t q4 = (size_t)blockIdx.x * 256 + threadIdx.x;
  const size_t e = q4 * 4;
  const int lrow = (int)(e >> 9);
  const float rn = inv_n[baseRow + lrow];
  float4 x = *(const float4*)(inp + (size_t)(baseRow + lrow) * FDIM + (e & 511));
  float xv[4] = {x.x, x.y, x.z, x.w};
  ushort4 hs, lo;
  #pragma unroll
  for (int q = 0; q < 4; ++q) {
    float v = xv[q] * rn;
    unsigned short hb = f2bf(v);
    ((unsigned short*)&hs)[q] = hb;
    ((unsigned short*)&lo)[q] = f2bf(v - bf2f(hb));
  }
  *(ushort4*)(Ah + e) = hs;
  *(ushort4*)(Al + e) = lo;
}

// ---------------- GEMM: C[M][N] = A[M][K] * B[N][K]^T, fp32 C ----------------
// SPLIT: hi/lo bf16 compensation (3 MFMA passes) for near-f32 accuracy.
template <bool SPLIT>
__global__ __launch_bounds__(256) void gemm_bt_k(
    const unsigned short* __restrict__ Ah, const unsigned short* __restrict__ Al,
    const unsigned short* __restrict__ Bh, const unsigned short* __restrict__ Bl,
    float* __restrict__ C, int M, int N, int K) {
  constexpr int LDT = 40;  // padded row (shorts): conflict-light
  __shared__ alignas(16) unsigned short sAh[128 * LDT];
  __shared__ alignas(16) unsigned short sBh[128 * LDT];
  __shared__ alignas(16) unsigned short sAl[SPLIT ? 128 * LDT : 8];
  __shared__ alignas(16) unsigned short sBl[SPLIT ? 128 * LDT : 8];

  const int tid = threadIdx.x;
  const int lane = tid & 63, wave = tid >> 6;
  const int wr = wave >> 1, wc = wave & 1;
  const int lr = lane & 15, ls = lane >> 4;
  const int m0 = blockIdx.y * 128, n0 = blockIdx.x * 128;

  f32x4 acc[4][4] = {};

  const int u0 = tid, u1 = tid + 256;
  const int r0 = u0 >> 2, c0e = (u0 & 3) * 8;
  const int r1 = u1 >> 2, c1e = (u1 & 3) * 8;

  const unsigned short* pAh0 = Ah + (size_t)(m0 + r0) * K + c0e;
  const unsigned short* pAh1 = Ah + (size_t)(m0 + r1) * K + c1e;
  const unsigned short* pBh0 = Bh + (size_t)(n0 + r0) * K + c0e;
  const unsigned short* pBh1 = Bh + (size_t)(n0 + r1) * K + c1e;
  const unsigned short* pAl0 = nullptr; const unsigned short* pAl1 = nullptr;
  const unsigned short* pBl0 = nullptr; const unsigned short* pBl1 = nullptr;

  u16x8 vAh0 = *(const u16x8*)pAh0, vAh1 = *(const u16x8*)pAh1;
  u16x8 vBh0 = *(const u16x8*)pBh0, vBh1 = *(const u16x8*)pBh1;
  u16x8 vAl0 = {}, vAl1 = {}, vBl0 = {}, vBl1 = {};
  if constexpr (SPLIT) {
    pAl0 = Al + (size_t)(m0 + r0) * K + c0e;
    pAl1 = Al + (size_t)(m0 + r1) * K + c1e;
    pBl0 = Bl + (size_t)(n0 + r0) * K + c0e;
    pBl1 = Bl + (size_t)(n0 + r1) * K + c1e;
    vAl0 = *(const u16x8*)pAl0; vAl1 = *(const u16x8*)pAl1;
    vBl0 = *(const u16x8*)pBl0; vBl1 = *(const u16x8*)pBl1;
  }

  const int nk = K >> 5;
  for (int ks = 0; ks < nk; ++ks) {
    *(u16x8*)&sAh[r0 * LDT + c0e] = vAh0;
    *(u16x8*)&sAh[r1 * LDT + c1e] = vAh1;
    *(u16x8*)&sBh[r0 * LDT + c0e] = vBh0;
    *(u16x8*)&sBh[r1 * LDT + c1e] = vBh1;
    if constexpr (SPLIT) {
      *(u16x8*)&sAl[r0 * LDT + c0e] = vAl0;
      *(u16x8*)&sAl[r1 * LDT + c1e] = vAl1;
      *(u16x8*)&sBl[r0 * LDT + c0e] = vBl0;
      *(u16x8*)&sBl[r1 * LDT + c1e] = vBl1;
    }
    __syncthreads();
    if (ks + 1 < nk) {
      pAh0 += 32; pAh1 += 32; pBh0 += 32; pBh1 += 32;
      vAh0 = *(const u16x8*)pAh0; vAh1 = *(const u16x8*)pAh1;
      vBh0 = *(const u16x8*)pBh0; vBh1 = *(const u16x8*)pBh1;
      if constexpr (SPLIT) {
        pAl0 += 32; pAl1 += 32; pBl0 += 32; pBl1 += 32;
        vAl0 = *(const u16x8*)pAl0; vAl1 = *(const u16x8*)pAl1;
        vBl0 = *(const u16x8*)pBl0; vBl1 = *(const u16x8*)pBl1;
      }
    }
    u16x8 fa[4], fb[4], fal[4], fbl[4];
    #pragma unroll
    for (int i = 0; i < 4; ++i) {
      fa[i] = *(const u16x8*)&sAh[(wr * 64 + i * 16 + lr) * LDT + ls * 8];
      fb[i] = *(const u16x8*)&sBh[(wc * 64 + i * 16 + lr) * LDT + ls * 8];
      if constexpr (SPLIT) {
        fal[i] = *(const u16x8*)&sAl[(wr * 64 + i * 16 + lr) * LDT + ls * 8];
        fbl[i] = *(const u16x8*)&sBl[(wc * 64 + i * 16 + lr) * LDT + ls * 8];
      }
    }
    #pragma unroll
    for (int i = 0; i < 4; ++i)
      #pragma unroll
      for (int j = 0; j < 4; ++j) {
        acc[i][j] = mfma16(fa[i], fb[j], acc[i][j]);
        if constexpr (SPLIT) {
          acc[i][j] = mfma16(fal[i], fb[j], acc[i][j]);
          acc[i][j] = mfma16(fa[i], fbl[j], acc[i][j]);
        }
      }
    __syncthreads();
  }

  #pragma unroll
  for (int i = 0; i < 4; ++i) {
    const int rrow = m0 + wr * 64 + i * 16 + ls * 4;
    #pragma unroll
    for (int j = 0; j < 4; ++j) {
      const int col = n0 + wc * 64 + j * 16 + lr;
      #pragma unroll
      for (int q = 0; q < 4; ++q)
        C[(size_t)(rrow + q) * N + col] = acc[i][j][q];
    }
  }
}

// -------- row softmax + top-2 + P(bf16) + scatter / queue ambiguous --------
__global__ __launch_bounds__(256) void softmax_scatter_k(
    const float* __restrict__ S, unsigned short* __restrict__ P,
    const float* __restrict__ inp, const float* __restrict__ inv_n,
    float* __restrict__ updates, int* __restrict__ queue,
    int* __restrict__ qcount, int baseRow) {
  const int widx = blockIdx.x * 4 + (threadIdx.x >> 6);
  const int lane = threadIdx.x & 63;
  const float* srow = S + (size_t)widx * MDIM;
  float4 v[8];
  float m1 = -3.4e38f, m2 = -3.4e38f;
  int i1 = 0x7fffffff, i2 = 0x7fffffff;
  #pragma unroll
  for (int i = 0; i < 8; ++i) {
    v[i] = *(const float4*)(srow + i * 256 + lane * 4);
    const float xs[4] = {v[i].x, v[i].y, v[i].z, v[i].w};
    #pragma unroll
    for (int q = 0; q < 4; ++q) {
      const float x = xs[q];
      const int idx = i * 256 + lane * 4 + q;
      if (x > m1 || (x == m1 && idx < i1)) { m2 = m1; i2 = i1; m1 = x; i1 = idx; }
      else if (x > m2 || (x == m2 && idx < i2)) { m2 = x; i2 = idx; }
    }
  }
  #pragma unroll
  for (int off = 1; off < 64; off <<= 1) {  // butterfly top-2 merge (disjoint groups)
    const float n1 = __shfl_xor(m1, off), n2 = __shfl_xor(m2, off);
    const int j1 = __shfl_xor(i1, off), j2 = __shfl_xor(i2, off);
    if (n1 > m1 || (n1 == m1 && j1 < i1)) {
      if (m1 > n2 || (m1 == n2 && i1 < j2)) { m2 = m1; i2 = i1; }
      else { m2 = n2; i2 = j2; }
      m1 = n1; i1 = j1;
    } else if (n1 > m2 || (n1 == m2 && j1 < i2)) { m2 = n1; i2 = j1; }
  }
  float sum = 0.0f;
  #pragma unroll
  for (int i = 0; i < 8; ++i) {
    v[i].x = __expf(SCALE_F * (v[i].x - m1)); sum += v[i].x;
    v[i].y = __expf(SCALE_F * (v[i].y - m1)); sum += v[i].y;
    v[i].z = __expf(SCALE_F * (v[i].z - m1)); sum += v[i].z;
    v[i].w = __expf(SCALE_F * (v[i].w - m1)); sum += v[i].w;
  }
  #pragma unroll
  for (int off = 1; off < 64; off <<= 1) sum += __shfl_xor(sum, off);
  const float rs = 1.0f / sum;
  #pragma unroll
  for (int i = 0; i < 8; ++i) {
    ushort4 pk;
    pk.x = f2bf(v[i].x * rs); pk.y = f2bf(v[i].y * rs);
    pk.z = f2bf(v[i].z * rs); pk.w = f2bf(v[i].w * rs);
    *(ushort4*)(P + (size_t)widx * MDIM + i * 256 + lane * 4) = pk;
  }
  const int tok = baseRow + widx;
  bool do_scatter = true;
  if (m1 - m2 < TAU_F) {  // ambiguous at f32-S noise scale -> full fp64 refine
    int slot = 0;
    if (lane == 0) slot = atomicAdd(qcount, 1);
    slot = __shfl(slot, 0);
    if (slot < QCAP) {
      if (lane == 0) queue[slot] = tok;
      do_scatter = false;
    }
  }
  if (do_scatter) {
    const float rn = inv_n[tok];
    const float* xrow = inp + (size_t)tok * FDIM;
    float* urow = updates + (size_t)i1 * FDIM;
    #pragma unroll
    for (int h = 0; h < 2; ++h) {
      float4 xv = *(const float4*)(xrow + h * 256 + lane * 4);
      const int e = h * 256 + lane * 4;
      atomicAdd(&urow[e + 0], xv.x * rn);
      atomicAdd(&urow[e + 1], xv.y * rn);
      atomicAdd(&urow[e + 2], xv.z * rn);
      atomicAdd(&urow[e + 3], xv.w * rn);
    }
  }
}

// ------- full-row fp64 argmax refine for queued tokens + scatter -------
// One block per queued token; each thread owns 8 memory rows; exact
// np.argmax semantics (strict >, smaller index on equality).
__global__ __launch_bounds__(256) void refine_k(
    const int* __restrict__ queue, const int* __restrict__ qcount,
    const float* __restrict__ inp, const float* __restrict__ mem,
    const double* __restrict__ dmninv, const float* __restrict__ inv_n,
    float* __restrict__ updates) {
  __shared__ float xs[FDIM];
  __shared__ double wbv[4];
  __shared__ int wbi[4];
  int cnt = *qcount; if (cnt > QCAP) cnt = QCAP;
  for (int q = blockIdx.x; q < cnt; q += gridDim.x) {
    const int tok = queue[q];
    const float* x = inp + (size_t)tok * FDIM;
    for (int f = threadIdx.x; f < FDIM; f += 256) xs[f] = x[f];
    __syncthreads();
    double bv = -1e300; int bi = 0x7fffffff;
    for (int r = 0; r < 8; ++r) {           // ascending m within thread
      const int m = r * 256 + threadIdx.x;
      const float* mr = mem + (size_t)m * FDIM;
      double d = 0.0;
      for (int f = 0; f < FDIM; f += 4) {
        const float4 mv = *(const float4*)(mr + f);
        d += (double)xs[f] * (double)mv.x;
        d += (double)xs[f + 1] * (double)mv.y;
        d += (double)xs[f + 2] * (double)mv.z;
        d += (double)xs[f + 3] * (double)mv.w;
      }
      d *= dmninv[m];
      if (d > bv || (d == bv && m < bi)) { bv = d; bi = m; }
    }
    #pragma unroll
    for (int off = 1; off < 64; off <<= 1) {
      const double ov = __shfl_xor(bv, off);
      const int oi = __shfl_xor(bi, off);
      if (ov > bv || (ov == bv && oi < bi)) { bv = ov; bi = oi; }
    }
    if ((threadIdx.x & 63) == 0) { wbv[threadIdx.x >> 6] = bv; wbi[threadIdx.x >> 6] = bi; }
    __syncthreads();
    double fv = wbv[0]; int fi = wbi[0];
    #pragma unroll
    for (int w = 1; w < 4; ++w)
      if (wbv[w] > fv || (wbv[w] == fv && wbi[w] < fi)) { fv = wbv[w]; fi = wbi[w]; }
    const float rn = inv_n[tok];
    for (int e = threadIdx.x; e < FDIM; e += 256)
      atomicAdd(&updates[(size_t)fi * FDIM + e], xs[e] * rn);
    __syncthreads();  // protect xs before next iteration's restage
  }
}

// ---------------- final blend (fp32 out) ----------------
__global__ __launch_bounds__(256) void final_update_k(
    const float* __restrict__ mem, const float* __restrict__ upd,
    float* __restrict__ out) {
  const size_t i = ((size_t)blockIdx.x * 256 + threadIdx.x) * 4;
  float4 m = *(const float4*)(mem + i);
  float4 u = *(const float4*)(upd + i);
  float4 r;
  r.x = m.x * 0.9f + u.x * 0.1f;
  r.y = m.y * 0.9f + u.y * 0.1f;
  r.z = m.z * 0.9f + u.z * 0.1f;
  r.w = m.w * 0.9f + u.w * 0.1f;
  *(float4*)(out + i) = r;
}

extern "C" void kernel_launch(void* const* d_in, const int* in_sizes, int n_in,
                              void* d_out, int out_size, void* d_ws, size_t ws_size,
                              hipStream_t stream) {
  const float* inputs = (const float*)d_in[0];
  const float* memory = (const float*)d_in[1];
  if (n_in >= 2 && in_sizes[0] != N_TOK * FDIM) {  // order guard
    inputs = (const float*)d_in[1];
    memory = (const float*)d_in[0];
  }
  float* out_mu = (float*)d_out;                       // [N][F] fp32
  float* out_um = out_mu + (size_t)N_TOK * FDIM;       // [M][F] fp32

  char* base = (char*)d_ws;
  size_t off = 0;
  auto take = [&](size_t bytes) -> char* {
    char* p = base + off;
    off = (off + bytes + 255) & ~(size_t)255;
    return p;
  };
  unsigned short* Bh = (unsigned short*)take((size_t)MDIM * FDIM * 2);
  unsigned short* Bl = (unsigned short*)take((size_t)MDIM * FDIM * 2);
  unsigned short* Bt = (unsigned short*)take((size_t)MDIM * FDIM * 2);
  float* inv_n = (float*)take((size_t)N_TOK * 4);
  double* dmninv = (double*)take((size_t)MDIM * 8);
  float* updates = (float*)take((size_t)MDIM * FDIM * 4);
  int* queue = (int*)take((size_t)QCAP * 4);
  int* qcount = (int*)take(256);
  const size_t fixed = off;

  int chunkT = 8192;  // per-pass token chunk; shrink to fit ws
  while (chunkT > 128 && fixed + (size_t)chunkT * 14336 + 4096 > ws_size)
    chunkT >>= 1;
  if (fixed + (size_t)chunkT * 14336 + 4096 > ws_size) return;  // ws too small

  unsigned short* Ah = (unsigned short*)take((size_t)chunkT * FDIM * 2);
  unsigned short* Al = (unsigned short*)take((size_t)chunkT * FDIM * 2);
  float* Sbuf = (float*)take((size_t)chunkT * MDIM * 4);
  unsigned short* Pbuf = (unsigned short*)take((size_t)chunkT * MDIM * 2);

  zero_k<<<(MDIM * FDIM / 4) / 256, 256, 0, stream>>>(updates, qcount);
  prep_memory_k<<<MDIM, 64, 0, stream>>>(memory, Bh, Bl);
  mem_norms64_k<<<MDIM / 4, 256, 0, stream>>>(memory, dmninv);
  transpose_k<<<dim3(MDIM / 32, FDIM / 32), 256, 0, stream>>>(Bh, Bt);
  input_norms_k<<<N_TOK / 4, 256, 0, stream>>>(inputs, inv_n);

  for (int baseRow = 0; baseRow < N_TOK; baseRow += chunkT) {
    prep_a_k<<<chunkT / 2, 256, 0, stream>>>(inputs, inv_n, Ah, Al, baseRow);
    gemm_bt_k<true><<<dim3(MDIM / 128, chunkT / 128), 256, 0, stream>>>(
        Ah, Al, Bh, Bl, Sbuf, chunkT, MDIM, FDIM);
    softmax_scatter_k<<<chunkT / 4, 256, 0, stream>>>(
        Sbuf, Pbuf, inputs, inv_n, updates, queue, qcount, baseRow);
    gemm_bt_k<false><<<dim3(FDIM / 128, chunkT / 128), 256, 0, stream>>>(
        Pbuf, nullptr, Bt, nullptr, out_mu + (size_t)baseRow * FDIM,
        chunkT, FDIM, MDIM);
  }
  refine_k<<<512, 256, 0, stream>>>(queue, qcount, inputs, memory, dmninv,
                                    inv_n, updates);
  final_update_k<<<(MDIM * FDIM / 4) / 256, 256, 0, stream>>>(memory, updates, out_um);
}